// Round 8
// baseline (175.644 us; speedup 1.0000x reference)
//
#include <hip/hip_runtime.h>
#include <float.h>

// VQ-VAE vector quantizer, MI355X fp32 vector-ALU version, round 9.
// z: [32,64,32,32] f32, codebook: [1024,64] f32
// out (f32 flat): z_q [2097152] | loss [1] | indices-as-float [32768]
//
// Numerics contract (DO NOT CHANGE — matches the fp32 ref's argmin exactly):
//  - code/pixel norms: numpy pairwise-sum tree over 64 rounded squares,
//    fp contract OFF (streamed 8-chunk form: r[j] = sum_m a[8m+j]^2
//    ascending m — identical element->partial grouping as the flat tree)
//  - dot: single c-ascending fma chain per (pixel, code)
//  - score: fl(fl(zz+ee) - 2*dot), strict-< first-min, ascending k,
//    wave w owns codes [w*128, w*128+128), ascending-wave lex-(v,i) merge
//
// Round-9 perf change — allocator ledger, final entry:
//   launch_bounds min-waves drives the backend's VGPR TARGET, not a cap:
//     (512,4) -> always 64 regs (8 waves/SIMD point) -> vz overflow SPILLS
//       (r8: +3.9 MB WRITE, 58% busy, 108 us)
//     (512,2) -> ~76 regs, overflow AGPR-parked, ZERO scratch (r0)
//   1 px/lane needs ~78 regs total -> under (512,2) it fits arch VGPRs
//   outright (no AGPR round-trips, unlike r0's 128-float z state).
// This round = round-8 kernel with launch_bounds(512,2). Grid 512 blocks
// = 2 blocks/CU = 16 waves/CU; VGPR-limited 512/~85 = 6 waves/SIMD > 4,
// so occupancy is preserved while the spill disappears.

#define DIM       64
#define N_EMB     1024
#define LOSS_OFF  2097152
#define IDX_OFF   2097153
// loss = 1.25 * sum / 2^21  (exact fp32 constant)
#define LOSS_SCALE 5.9604644775390625e-07f

// grid 512 blocks x 512 threads; block = 64 pixels (1/lane),
// 8 waves x 128-code slices
__global__ __launch_bounds__(512, 2)
void vq_main(const float* __restrict__ z, const float* __restrict__ cb,
             float* __restrict__ out, float* __restrict__ ws_partial) {
    __shared__ float esq[N_EMB];       // 4 KB
    __shared__ float cand_val[8 * 64]; // 2 KB
    __shared__ int   cand_idx[8 * 64]; // 2 KB
    __shared__ int   fidx[64];
    __shared__ float lred[8];

    const int tid  = threadIdx.x;
    const int lane = tid & 63;
    const int wave = __builtin_amdgcn_readfirstlane(tid >> 6);  // uniform
    const int n0   = blockIdx.x * 64;          // first pixel of this block
    const int b    = n0 >> 10;                 // batch image (1024 px each)
    const int hw0  = n0 & 1023;
    const size_t zbase = (size_t)b * 65536 + (size_t)hw0;  // z[b][c][hw]

    // ---- 1) codebook squared norms -> LDS (2 codes/thread), streamed ----
    // float4 locals -> scalars only; no stores into a float array (SROA-safe).
    {
        #pragma clang fp contract(off)
        for (int t = 0; t < 2; ++t) {
            const int k = tid * 2 + t;
            const float4* row = (const float4*)(cb + (size_t)k * DIM);
            float r[8];
            #pragma unroll
            for (int m = 0; m < 8; ++m) {
                const float4 x0 = row[2 * m];
                const float4 x1 = row[2 * m + 1];
                const float a0 = x0.x, a1 = x0.y, a2 = x0.z, a3 = x0.w;
                const float a4 = x1.x, a5 = x1.y, a6 = x1.z, a7 = x1.w;
                if (m == 0) {
                    r[0] = a0 * a0; r[1] = a1 * a1; r[2] = a2 * a2; r[3] = a3 * a3;
                    r[4] = a4 * a4; r[5] = a5 * a5; r[6] = a6 * a6; r[7] = a7 * a7;
                } else {
                    r[0] = r[0] + a0 * a0; r[1] = r[1] + a1 * a1;
                    r[2] = r[2] + a2 * a2; r[3] = r[3] + a3 * a3;
                    r[4] = r[4] + a4 * a4; r[5] = r[5] + a5 * a5;
                    r[6] = r[6] + a6 * a6; r[7] = r[7] + a7 * a7;
                }
            }
            esq[k] = ((r[0] + r[1]) + (r[2] + r[3]))
                   + ((r[4] + r[5]) + (r[6] + r[7]));
        }
    }

    // ---- 2) one pixel vector per lane + streamed zz (same numpy tree) ----
    float vz[DIM];
    float zz;
    {
        #pragma clang fp contract(off)
        float r[8];
        #pragma unroll
        for (int m = 0; m < 8; ++m) {
            #pragma unroll
            for (int j = 0; j < 8; ++j)
                vz[8 * m + j] = z[zbase + (size_t)(8 * m + j) * 1024 + lane];
            #pragma unroll
            for (int j = 0; j < 8; ++j) {
                const float p = vz[8 * m + j] * vz[8 * m + j];
                if (m == 0) r[j] = p; else r[j] = r[j] + p;
            }
        }
        zz = ((r[0] + r[1]) + (r[2] + r[3]))
           + ((r[4] + r[5]) + (r[6] + r[7]));
    }

    __syncthreads();

    // ---- 3) argmin over this wave's 128-code slice, 2 fma chains ----
    float best = FLT_MAX;
    int   bidx = 0;
    const int kbase = wave * 128;
    for (int k = kbase; k < kbase + 128; k += 2) {   // uniform k -> s_load rows
        const float* e0 = cb + (size_t)k * DIM;
        const float* e1 = e0 + DIM;
        float d0 = 0.f, d1 = 0.f;
        #pragma unroll
        for (int c = 0; c < DIM; ++c) {
            d0 = __builtin_fmaf(e0[c], vz[c], d0);   // code k
            d1 = __builtin_fmaf(e1[c], vz[c], d1);   // code k+1
        }
        float s0, s1;
        {
            #pragma clang fp contract(off)
            const float p0 = zz + esq[k];
            const float p1 = zz + esq[k + 1];
            s0 = p0 - 2.0f * d0;
            s1 = p1 - 2.0f * d1;
        }
        if (s0 < best) { best = s0; bidx = k; }      // ascending k =>
        if (s1 < best) { best = s1; bidx = k + 1; }  // first-min kept
    }
    cand_val[wave * 64 + lane] = best;
    cand_idx[wave * 64 + lane] = bidx;
    __syncthreads();

    // ---- 4) reduce 8 wave-candidates per pixel; write indices output ----
    if (tid < 64) {
        float bv = cand_val[tid];
        int   bi = cand_idx[tid];
        #pragma unroll
        for (int w = 1; w < 8; ++w) {
            float v = cand_val[w * 64 + tid];
            int   i = cand_idx[w * 64 + tid];
            if (v < bv || (v == bv && i < bi)) { bv = v; bi = i; }
        }
        fidx[tid] = bi;
        out[IDX_OFF + n0 + tid] = (float)bi;
    }
    __syncthreads();

    // ---- 5) z_q write (coalesced by hw) + loss partial ----
    // 512 threads: px = lane, wave cg handles channels cg*8 .. cg*8+7
    const int px = tid & 63;
    const int cg = tid >> 6;      // 0..7
    const int mi = fidx[px];
    float lacc = 0.f;
    #pragma unroll
    for (int i = 0; i < 8; ++i) {
        const int c = cg * 8 + i;
        float q  = cb[mi * DIM + c];                    // L2-resident gather
        size_t go = zbase + (size_t)c * 1024 + px;
        float zv = z[go];                               // coalesced, L1-hot
        float d  = q - zv;
        lacc = __builtin_fmaf(d, d, lacc);
        out[go] = q;                                    // coalesced
    }
    #pragma unroll
    for (int off = 32; off > 0; off >>= 1)
        lacc += __shfl_down(lacc, off, 64);
    if (lane == 0) lred[wave] = lacc;
    __syncthreads();
    if (tid == 0) {
        float t = 0.f;
        #pragma unroll
        for (int w = 0; w < 8; ++w) t += lred[w];
        ws_partial[blockIdx.x] = t;
    }
}

// single block, 512 threads: sum the 512 block partials -> loss
__global__ __launch_bounds__(512)
void vq_loss_finalize(const float* __restrict__ ws_partial, float* __restrict__ out) {
    __shared__ float red[8];
    const int tid = threadIdx.x;
    float v = ws_partial[tid];
    #pragma unroll
    for (int off = 32; off > 0; off >>= 1)
        v += __shfl_down(v, off, 64);
    const int lane = tid & 63, wave = tid >> 6;
    if (lane == 0) red[wave] = v;
    __syncthreads();
    if (tid == 0) {
        float t = 0.f;
        #pragma unroll
        for (int w = 0; w < 8; ++w) t += red[w];
        out[LOSS_OFF] = t * LOSS_SCALE;
    }
}

extern "C" void kernel_launch(void* const* d_in, const int* in_sizes, int n_in,
                              void* d_out, int out_size, void* d_ws, size_t ws_size,
                              hipStream_t stream) {
    const float* z  = (const float*)d_in[0];   // 2097152 f32
    const float* cb = (const float*)d_in[1];   // 65536 f32
    float* out = (float*)d_out;
    float* ws  = (float*)d_ws;                 // needs 512 * 4 B

    vq_main<<<512, 512, 0, stream>>>(z, cb, out, ws);
    vq_loss_finalize<<<1, 512, 0, stream>>>(ws, out);
}

// Round 9
// 158.867 us; speedup vs baseline: 1.1056x; 1.1056x over previous
//
#include <hip/hip_runtime.h>
#include <float.h>

// VQ-VAE vector quantizer, MI355X fp32 vector-ALU version, round 10.
// z: [32,64,32,32] f32, codebook: [1024,64] f32
// out (f32 flat): z_q [2097152] | loss [1] | indices-as-float [32768]
//
// Numerics contract (DO NOT CHANGE — matches the fp32 ref's argmin exactly):
//  - code/pixel norms: numpy pairwise-sum tree over 64 rounded squares,
//    fp contract OFF (streamed 8-chunk form: r[j] = sum_m a[8m+j]^2
//    ascending m — identical element->partial grouping as the flat tree)
//  - dot: single c-ascending fma chain per (pixel, code)
//  - score: fl(fl(zz+ee) - 2*dot), strict-< first-min, ascending k,
//    wave w owns codes [w*128, w*128+128), ascending-wave lex-(v,i) merge
//
// Round-10 perf change — allocator ledger, resolution:
//   r9 had IDEAL memory counters (FETCH 5.17/WRITE 8.35 MB, zero scratch)
//   yet busy-time 63 us = 2.3x the 27.3 us FMA floor at VGPR=72: vz[64]'s
//   overflow is AGPR-parked, every FMA pays a v_accvgpr_read. Pattern
//   across r0/r8/r9: the backend targets ~8 waves/EU REGARDLESS of the
//   launch_bounds minimum (which only caps the budget) and allocates
//   64-76 regs, dumping overflow to scratch/AGPR/L1-remat.
// Fix: PIN occupancy with amdgpu_waves_per_eu(4,4) — min=4 keeps budget
// at 128 regs, max=4 removes the incentive to allocate below it. 1 px/lane
// needs ~95 regs < 128 -> truly register-resident vz. Grid 512 blocks x
// 8 waves = 2 blocks/CU = exactly 4 waves/SIMD (2x round-0's hiding).
// Kernel body is byte-identical to round 9 (passed, clean counters).

#define DIM       64
#define N_EMB     1024
#define LOSS_OFF  2097152
#define IDX_OFF   2097153
// loss = 1.25 * sum / 2^21  (exact fp32 constant)
#define LOSS_SCALE 5.9604644775390625e-07f

// grid 512 blocks x 512 threads; block = 64 pixels (1/lane),
// 8 waves x 128-code slices
__global__ __launch_bounds__(512)
__attribute__((amdgpu_waves_per_eu(4, 4)))
void vq_main(const float* __restrict__ z, const float* __restrict__ cb,
             float* __restrict__ out, float* __restrict__ ws_partial) {
    __shared__ float esq[N_EMB];       // 4 KB
    __shared__ float cand_val[8 * 64]; // 2 KB
    __shared__ int   cand_idx[8 * 64]; // 2 KB
    __shared__ int   fidx[64];
    __shared__ float lred[8];

    const int tid  = threadIdx.x;
    const int lane = tid & 63;
    const int wave = __builtin_amdgcn_readfirstlane(tid >> 6);  // uniform
    const int n0   = blockIdx.x * 64;          // first pixel of this block
    const int b    = n0 >> 10;                 // batch image (1024 px each)
    const int hw0  = n0 & 1023;
    const size_t zbase = (size_t)b * 65536 + (size_t)hw0;  // z[b][c][hw]

    // ---- 1) codebook squared norms -> LDS (2 codes/thread), streamed ----
    // float4 locals -> scalars only; no stores into a float array (SROA-safe).
    {
        #pragma clang fp contract(off)
        for (int t = 0; t < 2; ++t) {
            const int k = tid * 2 + t;
            const float4* row = (const float4*)(cb + (size_t)k * DIM);
            float r[8];
            #pragma unroll
            for (int m = 0; m < 8; ++m) {
                const float4 x0 = row[2 * m];
                const float4 x1 = row[2 * m + 1];
                const float a0 = x0.x, a1 = x0.y, a2 = x0.z, a3 = x0.w;
                const float a4 = x1.x, a5 = x1.y, a6 = x1.z, a7 = x1.w;
                if (m == 0) {
                    r[0] = a0 * a0; r[1] = a1 * a1; r[2] = a2 * a2; r[3] = a3 * a3;
                    r[4] = a4 * a4; r[5] = a5 * a5; r[6] = a6 * a6; r[7] = a7 * a7;
                } else {
                    r[0] = r[0] + a0 * a0; r[1] = r[1] + a1 * a1;
                    r[2] = r[2] + a2 * a2; r[3] = r[3] + a3 * a3;
                    r[4] = r[4] + a4 * a4; r[5] = r[5] + a5 * a5;
                    r[6] = r[6] + a6 * a6; r[7] = r[7] + a7 * a7;
                }
            }
            esq[k] = ((r[0] + r[1]) + (r[2] + r[3]))
                   + ((r[4] + r[5]) + (r[6] + r[7]));
        }
    }

    // ---- 2) one pixel vector per lane + streamed zz (same numpy tree) ----
    float vz[DIM];
    float zz;
    {
        #pragma clang fp contract(off)
        float r[8];
        #pragma unroll
        for (int m = 0; m < 8; ++m) {
            #pragma unroll
            for (int j = 0; j < 8; ++j)
                vz[8 * m + j] = z[zbase + (size_t)(8 * m + j) * 1024 + lane];
            #pragma unroll
            for (int j = 0; j < 8; ++j) {
                const float p = vz[8 * m + j] * vz[8 * m + j];
                if (m == 0) r[j] = p; else r[j] = r[j] + p;
            }
        }
        zz = ((r[0] + r[1]) + (r[2] + r[3]))
           + ((r[4] + r[5]) + (r[6] + r[7]));
    }

    __syncthreads();

    // ---- 3) argmin over this wave's 128-code slice, 2 fma chains ----
    float best = FLT_MAX;
    int   bidx = 0;
    const int kbase = wave * 128;
    for (int k = kbase; k < kbase + 128; k += 2) {   // uniform k -> s_load rows
        const float* e0 = cb + (size_t)k * DIM;
        const float* e1 = e0 + DIM;
        float d0 = 0.f, d1 = 0.f;
        #pragma unroll
        for (int c = 0; c < DIM; ++c) {
            d0 = __builtin_fmaf(e0[c], vz[c], d0);   // code k
            d1 = __builtin_fmaf(e1[c], vz[c], d1);   // code k+1
        }
        float s0, s1;
        {
            #pragma clang fp contract(off)
            const float p0 = zz + esq[k];
            const float p1 = zz + esq[k + 1];
            s0 = p0 - 2.0f * d0;
            s1 = p1 - 2.0f * d1;
        }
        if (s0 < best) { best = s0; bidx = k; }      // ascending k =>
        if (s1 < best) { best = s1; bidx = k + 1; }  // first-min kept
    }
    cand_val[wave * 64 + lane] = best;
    cand_idx[wave * 64 + lane] = bidx;
    __syncthreads();

    // ---- 4) reduce 8 wave-candidates per pixel; write indices output ----
    if (tid < 64) {
        float bv = cand_val[tid];
        int   bi = cand_idx[tid];
        #pragma unroll
        for (int w = 1; w < 8; ++w) {
            float v = cand_val[w * 64 + tid];
            int   i = cand_idx[w * 64 + tid];
            if (v < bv || (v == bv && i < bi)) { bv = v; bi = i; }
        }
        fidx[tid] = bi;
        out[IDX_OFF + n0 + tid] = (float)bi;
    }
    __syncthreads();

    // ---- 5) z_q write (coalesced by hw) + loss partial ----
    // 512 threads: px = lane, wave cg handles channels cg*8 .. cg*8+7
    const int px = tid & 63;
    const int cg = tid >> 6;      // 0..7
    const int mi = fidx[px];
    float lacc = 0.f;
    #pragma unroll
    for (int i = 0; i < 8; ++i) {
        const int c = cg * 8 + i;
        float q  = cb[mi * DIM + c];                    // L2-resident gather
        size_t go = zbase + (size_t)c * 1024 + px;
        float zv = z[go];                               // coalesced, L1-hot
        float d  = q - zv;
        lacc = __builtin_fmaf(d, d, lacc);
        out[go] = q;                                    // coalesced
    }
    #pragma unroll
    for (int off = 32; off > 0; off >>= 1)
        lacc += __shfl_down(lacc, off, 64);
    if (lane == 0) lred[wave] = lacc;
    __syncthreads();
    if (tid == 0) {
        float t = 0.f;
        #pragma unroll
        for (int w = 0; w < 8; ++w) t += lred[w];
        ws_partial[blockIdx.x] = t;
    }
}

// single block, 512 threads: sum the 512 block partials -> loss
__global__ __launch_bounds__(512)
void vq_loss_finalize(const float* __restrict__ ws_partial, float* __restrict__ out) {
    __shared__ float red[8];
    const int tid = threadIdx.x;
    float v = ws_partial[tid];
    #pragma unroll
    for (int off = 32; off > 0; off >>= 1)
        v += __shfl_down(v, off, 64);
    const int lane = tid & 63, wave = tid >> 6;
    if (lane == 0) red[wave] = v;
    __syncthreads();
    if (tid == 0) {
        float t = 0.f;
        #pragma unroll
        for (int w = 0; w < 8; ++w) t += red[w];
        out[LOSS_OFF] = t * LOSS_SCALE;
    }
}

extern "C" void kernel_launch(void* const* d_in, const int* in_sizes, int n_in,
                              void* d_out, int out_size, void* d_ws, size_t ws_size,
                              hipStream_t stream) {
    const float* z  = (const float*)d_in[0];   // 2097152 f32
    const float* cb = (const float*)d_in[1];   // 65536 f32
    float* out = (float*)d_out;
    float* ws  = (float*)d_ws;                 // needs 512 * 4 B

    vq_main<<<512, 512, 0, stream>>>(z, cb, out, ws);
    vq_loss_finalize<<<1, 512, 0, stream>>>(ws, out);
}

// Round 10
// 131.515 us; speedup vs baseline: 1.3355x; 1.2080x over previous
//
#include <hip/hip_runtime.h>
#include <float.h>

// VQ-VAE vector quantizer, MI355X fp32 vector-ALU version, round 11.
// z: [32,64,32,32] f32, codebook: [1024,64] f32
// out (f32 flat): z_q [2097152] | loss [1] | indices-as-float [32768]
//
// Numerics contract (DO NOT CHANGE — bitwise-matches the numpy fp32 ref):
//  - code/pixel norms: numpy pairwise-sum tree over 64 rounded squares,
//    fp contract OFF
//  - dot: single k-ordered fma chain per (pixel, code)
//  - score: fl(fl(zz+ee) - 2*dot), strict-< first-min, ascending k,
//    wave w owns codes [w*128, w*128+128)
//
// Round-11 ledger synthesis: r0 (2px/lane, (512,2), budget 256) is the
// only config with near-floor VALU work (busy 34.5us vs 27.3us FMA floor;
// z parked in the unified VGPR/AGPR file, clean memory counters). Its sole
// defect: 44% utilization at 2 waves/SIMD — the 8x s_load_dwordx16 chunk
// sequence per 2-code step (SGPR ceiling ~102 forces chunking) can't hide
// under 256 FMAs with only one other wave to swap to. Shrinking per-lane
// state to raise occupancy always hit the 64-arch-VGPR allocator wall and
// RAISED busy-time (r8/r9/r10). So: keep r0's structure and halve the
// per-wave stall fraction instead — 4 codes per k-step = 8 independent
// chains = 512 FMAs overlapping each 1KB scalar-load sequence (2x compute
// per wait, 2x chain ILP). Selection order k,k+1,k+2,k+3 strict-< ==
// two consecutive 2-code steps: identical argmin.

#define DIM       64
#define N_EMB     1024
#define LOSS_OFF  2097152
#define IDX_OFF   2097153
// loss = 1.25 * sum / 2^21  (exact fp32 constant)
#define LOSS_SCALE 5.9604644775390625e-07f

// numpy pairwise_sum over 64 elements of a^2, exact tree.
__device__ __forceinline__ float np_sumsq64(const float* a) {
    #pragma clang fp contract(off)
    float r[8];
    #pragma unroll
    for (int j = 0; j < 8; ++j) {
        float s = a[j] * a[j];
        #pragma unroll
        for (int m = 1; m < 8; ++m) {
            float p = a[j + 8 * m] * a[j + 8 * m];
            s = s + p;
        }
        r[j] = s;
    }
    return ((r[0] + r[1]) + (r[2] + r[3])) + ((r[4] + r[5]) + (r[6] + r[7]));
}

// grid 256 blocks x 512 threads; block = 128 pixels (2/lane),
// 8 waves x 128-code slices
__global__ __launch_bounds__(512, 2)
void vq_main(const float* __restrict__ z, const float* __restrict__ cb,
             float* __restrict__ out, float* __restrict__ ws_partial) {
    __shared__ float esq[N_EMB];
    __shared__ float cand_val[8 * 128];
    __shared__ int   cand_idx[8 * 128];
    __shared__ int   fidx[128];
    __shared__ float lred[8];

    const int tid  = threadIdx.x;
    const int lane = tid & 63;
    const int wave = __builtin_amdgcn_readfirstlane(tid >> 6);  // uniform
    const int n0   = blockIdx.x * 128;         // first pixel of this block
    const int b    = n0 >> 10;                 // batch image (1024 px each)
    const int hw0  = n0 & 1023;
    const size_t zbase = (size_t)b * 65536 + (size_t)hw0;  // z[b][c][hw]

    // ---- 1) codebook squared norms -> LDS, numpy tree (2 codes/thread) ----
    {
        #pragma clang fp contract(off)
        for (int t = 0; t < 2; ++t) {
            const int k = tid * 2 + t;
            float a[DIM];
            const float4* row = (const float4*)(cb + (size_t)k * DIM);
            #pragma unroll
            for (int j = 0; j < 16; ++j) ((float4*)a)[j] = row[j];
            esq[k] = np_sumsq64(a);
        }
    }

    // ---- 2) two pixel vectors per lane (px0=lane, px1=lane+64) ----
    float vz0[DIM], vz1[DIM];
    #pragma unroll
    for (int c = 0; c < DIM; ++c) {
        vz0[c] = z[zbase + (size_t)c * 1024 + lane];        // coalesced
        vz1[c] = z[zbase + (size_t)c * 1024 + lane + 64];   // coalesced
    }
    const float zz0 = np_sumsq64(vz0);
    const float zz1 = np_sumsq64(vz1);

    __syncthreads();

    // ---- 3) argmin over this wave's 128-code slice, 8 fma chains ----
    float best0 = FLT_MAX, best1 = FLT_MAX;
    int   bidx0 = 0,       bidx1 = 0;
    const int kbase = wave * 128;
    for (int k = kbase; k < kbase + 128; k += 4) {   // uniform k -> s_load rows
        const float* e0 = cb + (size_t)k * DIM;
        const float* e1 = e0 + DIM;
        const float* e2 = e0 + 2 * DIM;
        const float* e3 = e0 + 3 * DIM;
        float d00 = 0.f, d01 = 0.f;     // code k,   px0/px1
        float d10 = 0.f, d11 = 0.f;     // code k+1
        float d20 = 0.f, d21 = 0.f;     // code k+2
        float d30 = 0.f, d31 = 0.f;     // code k+3
        #pragma unroll
        for (int c = 0; c < DIM; ++c) {
            const float a0 = e0[c];
            const float a1 = e1[c];
            const float a2 = e2[c];
            const float a3 = e3[c];
            const float zp0 = vz0[c];
            const float zp1 = vz1[c];
            d00 = __builtin_fmaf(a0, zp0, d00);
            d01 = __builtin_fmaf(a0, zp1, d01);
            d10 = __builtin_fmaf(a1, zp0, d10);
            d11 = __builtin_fmaf(a1, zp1, d11);
            d20 = __builtin_fmaf(a2, zp0, d20);
            d21 = __builtin_fmaf(a2, zp1, d21);
            d30 = __builtin_fmaf(a3, zp0, d30);
            d31 = __builtin_fmaf(a3, zp1, d31);
        }
        float s00, s01, s10, s11, s20, s21, s30, s31;
        {
            #pragma clang fp contract(off)
            const float p00 = zz0 + esq[k];
            const float p01 = zz1 + esq[k];
            const float p10 = zz0 + esq[k + 1];
            const float p11 = zz1 + esq[k + 1];
            const float p20 = zz0 + esq[k + 2];
            const float p21 = zz1 + esq[k + 2];
            const float p30 = zz0 + esq[k + 3];
            const float p31 = zz1 + esq[k + 3];
            s00 = p00 - 2.0f * d00;
            s01 = p01 - 2.0f * d01;
            s10 = p10 - 2.0f * d10;
            s11 = p11 - 2.0f * d11;
            s20 = p20 - 2.0f * d20;
            s21 = p21 - 2.0f * d21;
            s30 = p30 - 2.0f * d30;
            s31 = p31 - 2.0f * d31;
        }
        // ascending k, strict < => first-min kept (== two 2-code steps)
        if (s00 < best0) { best0 = s00; bidx0 = k; }
        if (s10 < best0) { best0 = s10; bidx0 = k + 1; }
        if (s20 < best0) { best0 = s20; bidx0 = k + 2; }
        if (s30 < best0) { best0 = s30; bidx0 = k + 3; }
        if (s01 < best1) { best1 = s01; bidx1 = k; }
        if (s11 < best1) { best1 = s11; bidx1 = k + 1; }
        if (s21 < best1) { best1 = s21; bidx1 = k + 2; }
        if (s31 < best1) { best1 = s31; bidx1 = k + 3; }
    }
    cand_val[wave * 128 + lane]      = best0;
    cand_idx[wave * 128 + lane]      = bidx0;
    cand_val[wave * 128 + 64 + lane] = best1;
    cand_idx[wave * 128 + 64 + lane] = bidx1;
    __syncthreads();

    // ---- 4) reduce 8 wave-candidates per pixel; write indices output ----
    if (tid < 128) {
        float bv = cand_val[tid];
        int   bi = cand_idx[tid];
        #pragma unroll
        for (int w = 1; w < 8; ++w) {
            float v = cand_val[w * 128 + tid];
            int   i = cand_idx[w * 128 + tid];
            if (v < bv || (v == bv && i < bi)) { bv = v; bi = i; }
        }
        fidx[tid] = bi;
        out[IDX_OFF + n0 + tid] = (float)bi;
    }
    __syncthreads();

    // ---- 5) z_q write (coalesced by hw) + loss partial ----
    const int px = tid & 127;
    const int cg = tid >> 7;      // 0..3 -> channels cg*16 .. cg*16+15
    const int mi = fidx[px];
    float lacc = 0.f;
    #pragma unroll
    for (int i = 0; i < 16; ++i) {
        const int c = cg * 16 + i;
        float q  = cb[mi * DIM + c];                    // L2-resident gather
        size_t go = zbase + (size_t)c * 1024 + px;
        float zv = z[go];                               // coalesced
        float d  = q - zv;
        lacc = __builtin_fmaf(d, d, lacc);
        out[go] = q;                                    // coalesced
    }
    #pragma unroll
    for (int off = 32; off > 0; off >>= 1)
        lacc += __shfl_down(lacc, off, 64);
    if (lane == 0) lred[wave] = lacc;
    __syncthreads();
    if (tid == 0) {
        float t = 0.f;
        #pragma unroll
        for (int w = 0; w < 8; ++w) t += lred[w];
        ws_partial[blockIdx.x] = t;
    }
}

// single block, 256 threads: sum the 256 block partials -> loss
__global__ __launch_bounds__(256)
void vq_loss_finalize(const float* __restrict__ ws_partial, float* __restrict__ out) {
    __shared__ float red[4];
    const int tid = threadIdx.x;
    float v = ws_partial[tid];
    #pragma unroll
    for (int off = 32; off > 0; off >>= 1)
        v += __shfl_down(v, off, 64);
    const int lane = tid & 63, wave = tid >> 6;
    if (lane == 0) red[wave] = v;
    __syncthreads();
    if (tid == 0) {
        float t = 0.f;
        #pragma unroll
        for (int w = 0; w < 4; ++w) t += red[w];
        out[LOSS_OFF] = t * LOSS_SCALE;
    }
}

extern "C" void kernel_launch(void* const* d_in, const int* in_sizes, int n_in,
                              void* d_out, int out_size, void* d_ws, size_t ws_size,
                              hipStream_t stream) {
    const float* z  = (const float*)d_in[0];   // 2097152 f32
    const float* cb = (const float*)d_in[1];   // 65536 f32
    float* out = (float*)d_out;
    float* ws  = (float*)d_ws;                 // needs 256 * 4 B

    vq_main<<<256, 512, 0, stream>>>(z, cb, out, ws);
    vq_loss_finalize<<<1, 256, 0, stream>>>(ws, out);
}